// Round 21
// baseline (102.533 us; speedup 1.0000x reference)
//
#include <hip/hip_runtime.h>
#include <hip/hip_bf16.h>

// B=2, S=2048, D=1024, H=16, HD=64. fp32 in, fp32 out, bf16-tolerance threshold.
// Pipeline: convert->bf16 | QKV GEMM (128x128 tile, 8 waves, BK=64 as 2 half-tiles,
//           1 barrier-pair per 16 MFMA; fused bias+RoPE; V transposed to Vt) |
//           V-prefix-sum | flash attn v9 (far via VPS) | out GEMM (split-K).

typedef unsigned short u16;
typedef short bf16x8 __attribute__((ext_vector_type(8)));
typedef float f32x4 __attribute__((ext_vector_type(4)));

__device__ __forceinline__ u16 f2bf(float f) {
    unsigned u = __builtin_bit_cast(unsigned, f);
    u += 0x7fffu + ((u >> 16) & 1u);   // RNE
    return (u16)(u >> 16);
}
__device__ __forceinline__ float bf2f(u16 h) {
    unsigned u = ((unsigned)h) << 16;
    return __builtin_bit_cast(float, u);
}

// ---------------- fused fp32 -> bf16 convert for all 5 tensors ---------------------
__global__ __launch_bounds__(256) void convert_all_k(const float* __restrict__ x,
                                                     const float* __restrict__ wq,
                                                     const float* __restrict__ wk,
                                                     const float* __restrict__ wv,
                                                     const float* __restrict__ wo_,
                                                     u16* __restrict__ xb,
                                                     u16* __restrict__ wqkv,
                                                     u16* __restrict__ wob) {
    int i = (blockIdx.x * 256 + threadIdx.x) * 4;
    const float* src;
    u16* dst;
    int off;
    if (i < 4194304) {
        src = x; dst = xb; off = i;
    } else if (i < 5242880) {
        src = wq; dst = wqkv; off = i - 4194304;
    } else if (i < 6291456) {
        src = wk; dst = wqkv + 1048576; off = i - 5242880;
    } else if (i < 7340032) {
        src = wv; dst = wqkv + 2097152; off = i - 6291456;
    } else {
        src = wo_; dst = wob; off = i - 7340032;
    }
    float4 v = *(const float4*)(src + off);
    uint2 o;
    o.x = (unsigned)f2bf(v.x) | ((unsigned)f2bf(v.y) << 16);
    o.y = (unsigned)f2bf(v.z) | ((unsigned)f2bf(v.w) << 16);
    *(uint2*)(dst + off) = o;
}

// ---------------- QKV GEMM: 128x128 tile, 8 waves, BK=64 (2 half-tiles) ------------
// Wave w: rows (w>>1)*32..+32, cols (w&1)*64..+64. Per K-step (64 wide): stage 4
// chunks/thread (A/B x half0/half1), ONE barrier pair, 16 MFMA (8 per half).
// Each half is the proven 128x32 layout (64B row stride). Grid 768; LDS 64KB ->
// 2 blocks/CU = 16 waves/CU.
__global__ __launch_bounds__(512, 2) void gemm_qkv(const u16* __restrict__ A,
                                                   const u16* __restrict__ Bw,
                                                   const float* __restrict__ bias0,
                                                   const float* __restrict__ bias1,
                                                   const float* __restrict__ bias2,
                                                   const int* __restrict__ days,
                                                   u16* __restrict__ outB,
                                                   u16* __restrict__ vt,
                                                   int M, int N, int K) {
    __shared__ __align__(16) u16 As[2][2][4096];   // [buf][half][128x32]
    __shared__ __align__(16) u16 Bs[2][2][4096];
    const int tid = threadIdx.x;
    const int lane = tid & 63;
    const int w = tid >> 6;          // 0..7
    const int wr = w >> 1, wc = w & 1;
    const int lr = lane & 15, lg = lane >> 4;
    const int nbn = N >> 7;          // 24
    const int wgid = (blockIdx.x & 7) * 96 + (blockIdx.x >> 3);  // XCD swizzle, 768=8x96
    const int m0 = (wgid / nbn) << 7;
    const int n0 = (wgid % nbn) << 7;

    f32x4 acc[2][4] = {};

    // staging: chunk cp = w*64+lane in [0,512); row cp>>2, k-col (cp&3)*8 within half
    const int cp = w * 64 + lane;
    const int arow = cp >> 2, kc = (cp & 3) << 3;
    const u16* aptr = A + (size_t)(m0 + arow) * K + kc;
    const u16* bptr = Bw + (size_t)(n0 + arow) * K + kc;
    const int coff = cp * 8;

#define GSTAGE(K0, BUF)                                                                \
    do {                                                                               \
        __builtin_amdgcn_global_load_lds(                                              \
            (const __attribute__((address_space(1))) void*)(aptr + (K0)),              \
            (__attribute__((address_space(3))) void*)(&As[BUF][0][coff]), 16, 0, 0);   \
        __builtin_amdgcn_global_load_lds(                                              \
            (const __attribute__((address_space(1))) void*)(aptr + (K0) + 32),         \
            (__attribute__((address_space(3))) void*)(&As[BUF][1][coff]), 16, 0, 0);   \
        __builtin_amdgcn_global_load_lds(                                              \
            (const __attribute__((address_space(1))) void*)(bptr + (K0)),              \
            (__attribute__((address_space(3))) void*)(&Bs[BUF][0][coff]), 16, 0, 0);   \
        __builtin_amdgcn_global_load_lds(                                              \
            (const __attribute__((address_space(1))) void*)(bptr + (K0) + 32),         \
            (__attribute__((address_space(3))) void*)(&Bs[BUF][1][coff]), 16, 0, 0);   \
    } while (0)

    const int nks = K >> 6;  // 16 steps of BK=64
    GSTAGE(0, 0);
    for (int ks = 0; ks < nks; ++ks) {
        const int cur = ks & 1;
        if (ks + 1 < nks) {
            GSTAGE((ks + 1) * 64, cur ^ 1);
            asm volatile("s_waitcnt vmcnt(4)" ::: "memory");
        } else {
            asm volatile("s_waitcnt vmcnt(0)" ::: "memory");
        }
        __builtin_amdgcn_s_barrier();
#pragma unroll
        for (int hf = 0; hf < 2; ++hf) {
            bf16x8 af[2], bfr[4];
#pragma unroll
            for (int i = 0; i < 2; ++i)
                af[i] = *(const bf16x8*)(&As[cur][hf][(wr * 32 + i * 16 + lr) * 32 + lg * 8]);
#pragma unroll
            for (int j = 0; j < 4; ++j)
                bfr[j] = *(const bf16x8*)(&Bs[cur][hf][(wc * 64 + j * 16 + lr) * 32 + lg * 8]);
#pragma unroll
            for (int i = 0; i < 2; ++i)
#pragma unroll
                for (int j = 0; j < 4; ++j)
                    acc[i][j] = __builtin_amdgcn_mfma_f32_16x16x32_bf16(af[i], bfr[j],
                                                                        acc[i][j], 0, 0, 0);
        }
        __builtin_amdgcn_s_barrier();
    }
#undef GSTAGE

    auto bsel = [&](int ng) -> float {
        return (ng < 1024) ? bias0[ng] : (ng < 2048) ? bias1[ng - 1024] : bias2[ng - 2048];
    };

    if ((n0 + wc * 64) < 2048) {
        // q/k region: wave's 64 cols = one full head; pairs (j, j+2) hold (x1, x2).
        const float C1 = -0.41524101186091903f;  // -log2(10000)/32
        const float inv0 = exp2f((float)lr * C1);
        const float inv1 = exp2f((float)(16 + lr) * C1);
#pragma unroll
        for (int i = 0; i < 2; ++i) {
            int mg = m0 + wr * 32 + i * 16 + lg * 4;
#pragma unroll
            for (int r = 0; r < 4; ++r) {
                int m = mg + r;
                int d = days[m];
                int ad = d < 0 ? -d : d;
                ad = ad > 2047 ? 2047 : ad;
                float pos = (float)ad;
#pragma unroll
                for (int j = 0; j < 2; ++j) {
                    int ng1 = n0 + wc * 64 + j * 16 + lr;
                    int ng2 = ng1 + 32;
                    float x1 = acc[i][j][r] + bsel(ng1);
                    float x2 = acc[i][j + 2][r] + bsel(ng2);
                    float ang = pos * (j ? inv1 : inv0);
                    float sn, cs;
                    __sincosf(ang, &sn, &cs);
                    outB[(size_t)m * 2048 + ng1] = f2bf(x1 * cs - x2 * sn);
                    outB[(size_t)m * 2048 + ng2] = f2bf(x2 * cs + x1 * sn);
                }
            }
        }
    } else {
        // V region: write transposed into vt[bh][hd][s]; 4 consecutive s packed 8B.
        const int h = ((n0 + wc * 64) - 2048) >> 6;
#pragma unroll
        for (int i = 0; i < 2; ++i) {
            int mg = m0 + wr * 32 + i * 16 + lg * 4;
            int b = mg >> 11, s0 = mg & 2047;
#pragma unroll
            for (int j = 0; j < 4; ++j) {
                int hd = j * 16 + lr;
                int ng = 2048 + h * 64 + hd;
                float bias = bsel(ng);
                ushort4 o;
                o.x = f2bf(acc[i][j][0] + bias);
                o.y = f2bf(acc[i][j][1] + bias);
                o.z = f2bf(acc[i][j][2] + bias);
                o.w = f2bf(acc[i][j][3] + bias);
                *(ushort4*)&vt[((size_t)(b * 16 + h) * 64 + hd) * 2048 + s0] = o;
            }
        }
    }
}

// ---------------- out-proj GEMM: split-K across 2 wave-groups ----------------------
__global__ __launch_bounds__(512, 2) void gemm_out(const u16* __restrict__ A,
                                                   const u16* __restrict__ Bw,
                                                   const float* __restrict__ bias0,
                                                   float* __restrict__ outF,
                                                   int M, int N, int K) {
    __shared__ __align__(16) u16 As[2][2][4096];  // [group][buf]
    __shared__ __align__(16) u16 Bs[2][2][4096];
    const int tid = threadIdx.x;
    const int lane = tid & 63;
    const int w4 = (tid >> 6) & 3;
    const int g = tid >> 8;
    const int wr = w4 >> 1, wc = w4 & 1;
    const int lr = lane & 15, lg = lane >> 4;
    const int nbn = N >> 7;
    const int m0 = (blockIdx.x / nbn) << 7;
    const int n0 = (blockIdx.x % nbn) << 7;
    const int kbase = g * (K >> 1);

    f32x4 acc[4][4] = {};

    const u16* aptr[2];
    const u16* bptr[2];
    int ldsoff[2];
#pragma unroll
    for (int i = 0; i < 2; ++i) {
        int c = (w4 * 2 + i) * 64 + lane;
        int row = c >> 2, kc = (c & 3) << 3;
        aptr[i] = A + (size_t)(m0 + row) * K + kbase + kc;
        bptr[i] = Bw + (size_t)(n0 + row) * K + kbase + kc;
        ldsoff[i] = (w4 * 2 + i) * 512;
    }

#define GSTAGE(K0, BUF)                                                                \
    do {                                                                               \
        _Pragma("unroll") for (int i = 0; i < 2; ++i) {                                \
            __builtin_amdgcn_global_load_lds(                                          \
                (const __attribute__((address_space(1))) void*)(aptr[i] + (K0)),       \
                (__attribute__((address_space(3))) void*)(&As[g][BUF][ldsoff[i]]), 16, \
                0, 0);                                                                 \
            __builtin_amdgcn_global_load_lds(                                          \
                (const __attribute__((address_space(1))) void*)(bptr[i] + (K0)),       \
                (__attribute__((address_space(3))) void*)(&Bs[g][BUF][ldsoff[i]]), 16, \
                0, 0);                                                                 \
        }                                                                              \
    } while (0)

    const int nks = K >> 6;  // per-group steps = 16
    GSTAGE(0, 0);
    for (int ks = 0; ks < nks; ++ks) {
        const int cur = ks & 1;
        if (ks + 1 < nks) {
            GSTAGE((ks + 1) * 32, cur ^ 1);
            asm volatile("s_waitcnt vmcnt(4)" ::: "memory");
        } else {
            asm volatile("s_waitcnt vmcnt(0)" ::: "memory");
        }
        __builtin_amdgcn_s_barrier();
        bf16x8 af[4], bfr[4];
#pragma unroll
        for (int i = 0; i < 4; ++i)
            af[i] = *(const bf16x8*)(&As[g][cur][(wr * 64 + i * 16 + lr) * 32 + lg * 8]);
#pragma unroll
        for (int j = 0; j < 4; ++j)
            bfr[j] = *(const bf16x8*)(&Bs[g][cur][(wc * 64 + j * 16 + lr) * 32 + lg * 8]);
#pragma unroll
        for (int i = 0; i < 4; ++i)
#pragma unroll
            for (int j = 0; j < 4; ++j)
                acc[i][j] = __builtin_amdgcn_mfma_f32_16x16x32_bf16(af[i], bfr[j],
                                                                    acc[i][j], 0, 0, 0);
        __builtin_amdgcn_s_barrier();
    }
#undef GSTAGE

    float* xch = (float*)&As[0][0][0];
    const int t256 = tid & 255;
#pragma unroll
    for (int hf = 0; hf < 2; ++hf) {
        __syncthreads();
        if (g == 1) {
#pragma unroll
            for (int i = 0; i < 2; ++i)
#pragma unroll
                for (int j = 0; j < 4; ++j)
                    *(f32x4*)&xch[((t256 * 8) + i * 4 + j) * 4] = acc[hf * 2 + i][j];
        }
        __syncthreads();
        if (g == 0) {
#pragma unroll
            for (int i = 0; i < 2; ++i)
#pragma unroll
                for (int j = 0; j < 4; ++j)
                    acc[hf * 2 + i][j] += *(const f32x4*)&xch[((t256 * 8) + i * 4 + j) * 4];
        }
    }
    if (g == 0) {
#pragma unroll
        for (int i = 0; i < 4; ++i) {
            int mg = m0 + wr * 64 + i * 16 + lg * 4;
#pragma unroll
            for (int j = 0; j < 4; ++j) {
                int ng = n0 + wc * 64 + j * 16 + lr;
                float bias = bias0[ng];
#pragma unroll
                for (int r = 0; r < 4; ++r)
                    outF[(size_t)(mg + r) * N + ng] = acc[i][j][r] + bias;
            }
        }
    }
}

// ---------------- V prefix sums over k-tiles: VPS[bh][t][d], t in [0,32] -----------
__global__ __launch_bounds__(256) void vps_k(const u16* __restrict__ vt,
                                             float* __restrict__ vps) {
    __shared__ float ts[32][32];
    const int bh = blockIdx.x >> 1;
    const int d0 = (blockIdx.x & 1) * 32;
    const int dl = threadIdx.x >> 3;
    const int seg = threadIdx.x & 7;
    const u16* vrow = vt + ((size_t)bh * 64 + d0 + dl) * 2048 + seg * 256;
#pragma unroll
    for (int tt = 0; tt < 4; ++tt) {
        float s = 0.f;
#pragma unroll
        for (int i = 0; i < 8; ++i) {
            bf16x8 v = *(const bf16x8*)(vrow + tt * 64 + i * 8);
#pragma unroll
            for (int e = 0; e < 8; ++e) s += bf2f((u16)v[e]);
        }
        ts[dl][seg * 4 + tt] = s;
    }
    __syncthreads();
    if (threadIdx.x < 32) {
        int d = threadIdx.x;
        float acc = 0.f;
        for (int t = 0; t <= 32; ++t) {
            vps[((size_t)bh * 33 + t) * 64 + d0 + d] = acc;
            if (t < 32) acc += ts[d][t];
        }
    }
}

// ---------------- flash attention v9 -----------------------------------------------
__device__ __forceinline__ void attn_tile(const u16* __restrict__ Ks,
                                          const u16* __restrict__ Vs,
                                          u16* __restrict__ Pw,
                                          const int* __restrict__ dbk,
                                          float dkmax_c, bf16x8 pconst, float pcr,
                                          bf16x8 bq0, bf16x8 bq1, float dq_c, float c1,
                                          int qrel, bool domask,
                                          float& l_part, f32x4* acc, int lr, int lg) {
    if (!domask && __all(dkmax_c - dq_c < -20.0f)) {
        l_part += 16.0f * pcr;
        __builtin_amdgcn_s_setprio(1);
#pragma unroll
        for (int pv = 0; pv < 2; ++pv) {
            int chunk = pv * 4 + lg;
#pragma unroll
            for (int c = 0; c < 4; ++c) {
                const int r3 = c * 16 + lr;
                bf16x8 bv = *(const bf16x8*)(Vs + r3 * 64 + ((chunk ^ (r3 & 7)) << 3));
                acc[c] = __builtin_amdgcn_mfma_f32_16x16x32_bf16(pconst, bv, acc[c], 0, 0, 0);
            }
        }
        __builtin_amdgcn_s_setprio(0);
        return;
    }
    f32x4 st_acc[4];
    __builtin_amdgcn_s_setprio(1);
#pragma unroll
    for (int st = 0; st < 4; ++st) {
        const int r2 = st * 16 + lr;
        const u16* kr = Ks + r2 * 64;
        bf16x8 ka0 = *(const bf16x8*)(kr + ((lg ^ (r2 & 7)) << 3));
        bf16x8 ka1 = *(const bf16x8*)(kr + (((4 + lg) ^ (r2 & 7)) << 3));
        f32x4 t = {};
        t = __builtin_amdgcn_mfma_f32_16x16x32_bf16(ka0, bq0, t, 0, 0, 0);
        t = __builtin_amdgcn_mfma_f32_16x16x32_bf16(ka1, bq1, t, 0, 0, 0);
        st_acc[st] = t;
    }
    __builtin_amdgcn_s_setprio(0);
    const float L2E = 1.4426950408889634f;
    const float POFF = 17.312340490667562f;  // 12*log2(e)
    float p[4][4];
#pragma unroll
    for (int st = 0; st < 4; ++st) {
        int4 dk4 = *(const int4*)(dbk + st * 16 + lg * 4);
#pragma unroll
        for (int r = 0; r < 4; ++r) {
            float dkf = (float)((&dk4.x)[r]);
            float dec = exp2f(__builtin_fmaf(dkf, c1, -dq_c));  // decay/8
            float v = st_acc[st][r] * dec;
            p[st][r] = exp2f(__builtin_fmaf(v, L2E, -POFF));
        }
    }
    if (domask) {
#pragma unroll
        for (int st = 0; st < 4; ++st)
#pragma unroll
            for (int r = 0; r < 4; ++r)
                p[st][r] = (st * 16 + lg * 4 + r <= qrel) ? p[st][r] : 0.f;
    }
#pragma unroll
    for (int st = 0; st < 4; ++st)
#pragma unroll
        for (int r = 0; r < 4; ++r) l_part += p[st][r];
#pragma unroll
    for (int st = 0; st < 4; ++st) {
        unsigned lo, hi;
        asm("v_cvt_pk_bf16_f32 %0, %1, %2" : "=v"(lo) : "v"(p[st][0]), "v"(p[st][1]));
        asm("v_cvt_pk_bf16_f32 %0, %1, %2" : "=v"(hi) : "v"(p[st][2]), "v"(p[st][3]));
        uint2 pk;
        pk.x = lo;
        pk.y = hi;
        int chunk = st * 2 + (lg >> 1);
        int idx = lr * 64 + ((chunk ^ (lr & 7)) << 3) + ((lg & 1) << 2);
        *(uint2*)&Pw[idx] = pk;
    }
    __builtin_amdgcn_s_setprio(1);
#pragma unroll
    for (int pv = 0; pv < 2; ++pv) {
        int chunk = pv * 4 + lg;
        bf16x8 pa = *(const bf16x8*)&Pw[lr * 64 + ((chunk ^ (lr & 7)) << 3)];
#pragma unroll
        for (int c = 0; c < 4; ++c) {
            const int r3 = c * 16 + lr;
            bf16x8 bv = *(const bf16x8*)(Vs + r3 * 64 + ((chunk ^ (r3 & 7)) << 3));
            acc[c] = __builtin_amdgcn_mfma_f32_16x16x32_bf16(pa, bv, acc[c], 0, 0, 0);
        }
    }
    __builtin_amdgcn_s_setprio(0);
}

__global__ __launch_bounds__(256, 4) void attn_k(const u16* __restrict__ qkv,
                                                 const u16* __restrict__ vt,
                                                 const int* __restrict__ days,
                                                 const float* __restrict__ decay_p,
                                                 const float* __restrict__ vps,
                                                 u16* __restrict__ attn_out) {
    __shared__ __align__(16) u16 Ks[2][4096];
    __shared__ __align__(16) u16 Vs[2][4096];
    __shared__ __align__(16) u16 Plds[4][1024];
    const int tid = threadIdx.x;
    const int lane = tid & 63;
    const int w = tid >> 6;
    const int lr = lane & 15, lg = lane >> 4;
    const int wg = (blockIdx.x & 7) * 128 + (blockIdx.x >> 3);
    const int qt = wg & 31;
    const int bh = wg >> 5;
    const int b = bh >> 4, h = bh & 15;
    const int qb = qt * 64 + w * 16;
    const float rate = decay_p[0];
    const float c1 = rate * 1.4426950408889634f;

    // q|k buffer: rows [4096], stride 2048 (q cols 0..1023, k cols 1024..2047)
    const u16* qmat = qkv + (size_t)b * 2048 * 2048 + h * 64;
    const u16* kmat = qmat + 1024;
    const u16* vtm = vt + (size_t)bh * 64 * 2048;
    const int* db = days + b * 2048;

    const int cp0 = (w * 2 + 0) * 64 + lane;
    const int cp1 = (w * 2 + 1) * 64 + lane;
    const int r0 = cp0 >> 3, c0 = cp0 & 7;
    const int r1 = cp1 >> 3, c1i = cp1 & 7;
    const u16* ksrc0 = kmat + (size_t)r0 * 2048 + ((c0 ^ (r0 & 7)) << 3);
    const u16* ksrc1 = kmat + (size_t)r1 * 2048 + ((c1i ^ (r1 & 7)) << 3);
    const u16* vsrc0 = vtm + (size_t)r0 * 2048 + ((c0 ^ (r0 & 7)) << 3);
    const u16* vsrc1 = vtm + (size_t)r1 * 2048 + ((c1i ^ (r1 & 7)) << 3);
    const int doff0 = (w * 2 + 0) * 512;
    const int doff1 = (w * 2 + 1) * 512;

#define STAGE(T, SLOT)                                                                 \
    do {                                                                               \
        __builtin_amdgcn_global_load_lds(                                              \
            (const __attribute__((address_space(1))) void*)(ksrc0 +                    \
                                                            (size_t)(T) * 64 * 2048), \
            (__attribute__((address_space(3))) void*)(&Ks[SLOT][doff0]), 16, 0, 0);    \
        __builtin_amdgcn_global_load_lds(                                              \
            (const __attribute__((address_space(1))) void*)(ksrc1 +                    \
                                                            (size_t)(T) * 64 * 2048), \
            (__attribute__((address_space(3))) void*)(&Ks[SLOT][doff1]), 16, 0, 0);    \
        __builtin_amdgcn_global_load_lds(                                              \
            (const __attribute__((address_space(1))) void*)(vsrc0 + (size_t)(T) * 64), \
            (__attribute__((address_space(3))) void*)(&Vs[SLOT][doff0]), 16, 0, 0);    \
        __builtin_amdgcn_global_load_lds(                                              \
            (const __attribute__((address_space(1))) void*)(vsrc1 + (size_t)(T) * 64), \
            (__attribute__((address_space(3))) void*)(&Vs[SLOT][doff1]), 16, 0, 0);    \
    } while (0)

    const float dq00_c = (float)db[qt * 64] * c1 + 3.0f;
    int t0;
    {
        const int l32 = lane & 31;
        float dm = (float)db[l32 * 64 + 63] * c1;
        bool cnd = (lane < qt) && (dm < dq00_c - 20.0f);
        unsigned long long m = __ballot(cnd);
        t0 = (int)__builtin_ctzll(~m);
    }

    STAGE(t0, 0);

    bf16x8 bq0, bq1;
    {
        const u16* qp = qmat + (size_t)(qb + lr) * 2048 + lg * 8;
        bq0 = *(const bf16x8*)qp;
        bq1 = *(const bf16x8*)(qp + 32);
    }
    const float dq_c = (float)db[qb + lr] * c1 + 3.0f;

    const u16 pcu = f2bf(exp2f(-17.312340490667562f));
    const float pcr = bf2f(pcu);
    bf16x8 pconst;
#pragma unroll
    for (int i = 0; i < 8; ++i) pconst[i] = (short)pcu;

    float lp = (float)t0 * 16.0f * pcr;
    f32x4 acc[4];
#pragma unroll
    for (int c = 0; c < 4; ++c) {
        float vv = pcr * vps[((size_t)bh * 33 + t0) * 64 + c * 16 + lr];
        acc[c] = (f32x4){vv, vv, vv, vv};
    }

    for (int kt = t0; kt <= qt; ++kt) {
        const int cur = (kt - t0) & 1;
        if (kt < qt) {
            STAGE(kt + 1, cur ^ 1);
            asm volatile("s_waitcnt vmcnt(4)" ::: "memory");
        } else {
            asm volatile("s_waitcnt vmcnt(0)" ::: "memory");
        }
        __builtin_amdgcn_s_barrier();
        const int* dbk = days + b * 2048 + kt * 64;
        const float dkmax_c = (float)dbk[63] * c1;
        attn_tile(Ks[cur], Vs[cur], Plds[w], dbk, dkmax_c, pconst, pcr,
                  bq0, bq1, dq_c, c1, w * 16 + lr, kt == qt, lp, acc, lr, lg);
        __builtin_amdgcn_s_barrier();
    }
#undef STAGE

    float l_full = lp + __shfl_xor(lp, 16);
    l_full += __shfl_xor(l_full, 32);
    float inv_[4];
#pragma unroll
    for (int r = 0; r < 4; ++r) inv_[r] = 1.0f / __shfl(l_full, lg * 4 + r);
#pragma unroll
    for (int c = 0; c < 4; ++c)
#pragma unroll
        for (int r = 0; r < 4; ++r) {
            const int qg = qb + lg * 4 + r;
            attn_out[(size_t)(b * 2048 + qg) * 1024 + h * 64 + c * 16 + lr] =
                f2bf(acc[c][r] * inv_[r]);
        }
}

// ---------------- launch -----------------------------------------------------------
extern "C" void kernel_launch(void* const* d_in, const int* in_sizes, int n_in,
                              void* d_out, int out_size, void* d_ws, size_t ws_size,
                              hipStream_t stream) {
    const float* x = (const float*)d_in[0];
    const float* Wq = (const float*)d_in[1];
    const float* bq = (const float*)d_in[2];
    const float* Wk = (const float*)d_in[3];
    const float* bk = (const float*)d_in[4];
    const float* Wv = (const float*)d_in[5];
    const float* bv = (const float*)d_in[6];
    const float* Wo = (const float*)d_in[7];
    const float* bo = (const float*)d_in[8];
    const float* decay = (const float*)d_in[9];
    const int* days = (const int*)d_in[11];
    float* out = (float*)d_out;

    char* ws = (char*)d_ws;
    u16* xb = (u16*)(ws);                   //  8 MB: x bf16 [4096][1024]
    u16* wqkv = (u16*)(ws + 8388608);       //  6 MB: [Wq;Wk;Wv] bf16 [3072][1024]
    u16* wo = (u16*)(ws + 14680064);        //  2 MB: Wo bf16 [1024][1024]
    u16* qkb = (u16*)(ws + 16777216);       // 16 MB: q|k bf16 [4096][2048]
    u16* vtb = (u16*)(ws + 41943040);       //  8 MB: Vt bf16 [32][64][2048]
    u16* attb = (u16*)(ws + 50331648);      //  8 MB: attn out bf16 [4096][1024]
    float* vpsb = (float*)(ws + 58720256);  // 270 KB: V prefix sums [32][33][64] f32

    convert_all_k<<<8192, 256, 0, stream>>>(x, Wq, Wk, Wv, Wo, xb, wqkv, wo);

    gemm_qkv<<<768, 512, 0, stream>>>(xb, wqkv, bq, bk, bv, days, qkb, vtb, 4096,
                                      3072, 1024);
    vps_k<<<64, 256, 0, stream>>>(vtb, vpsb);
    attn_k<<<1024, 256, 0, stream>>>(qkb, vtb, days, decay, vpsb, attb);
    gemm_out<<<256, 512, 0, stream>>>(attb, wo, bo, out, 4096, 1024, 1024);
}

// Round 22
// 96.659 us; speedup vs baseline: 1.0608x; 1.0608x over previous
//
#include <hip/hip_runtime.h>
#include <hip/hip_bf16.h>

// B=2, S=2048, D=1024, H=16, HD=64. fp32 in, fp32 out, bf16-tolerance threshold.
// Pipeline: convert->bf16 | QKV GEMM (128x128 tile, 8 waves, 3-slot ring LDS,
//           ONE barrier per K-step; fused bias+RoPE; V transposed to Vt) |
//           V-prefix-sum | flash attn v9 (far via VPS) | out GEMM (split-K, ring).

typedef unsigned short u16;
typedef short bf16x8 __attribute__((ext_vector_type(8)));
typedef float f32x4 __attribute__((ext_vector_type(4)));

__device__ __forceinline__ u16 f2bf(float f) {
    unsigned u = __builtin_bit_cast(unsigned, f);
    u += 0x7fffu + ((u >> 16) & 1u);   // RNE
    return (u16)(u >> 16);
}
__device__ __forceinline__ float bf2f(u16 h) {
    unsigned u = ((unsigned)h) << 16;
    return __builtin_bit_cast(float, u);
}

// ---------------- fused fp32 -> bf16 convert for all 5 tensors ---------------------
__global__ __launch_bounds__(256) void convert_all_k(const float* __restrict__ x,
                                                     const float* __restrict__ wq,
                                                     const float* __restrict__ wk,
                                                     const float* __restrict__ wv,
                                                     const float* __restrict__ wo_,
                                                     u16* __restrict__ xb,
                                                     u16* __restrict__ wqkv,
                                                     u16* __restrict__ wob) {
    int i = (blockIdx.x * 256 + threadIdx.x) * 4;
    const float* src;
    u16* dst;
    int off;
    if (i < 4194304) {
        src = x; dst = xb; off = i;
    } else if (i < 5242880) {
        src = wq; dst = wqkv; off = i - 4194304;
    } else if (i < 6291456) {
        src = wk; dst = wqkv + 1048576; off = i - 5242880;
    } else if (i < 7340032) {
        src = wv; dst = wqkv + 2097152; off = i - 6291456;
    } else {
        src = wo_; dst = wob; off = i - 7340032;
    }
    float4 v = *(const float4*)(src + off);
    uint2 o;
    o.x = (unsigned)f2bf(v.x) | ((unsigned)f2bf(v.y) << 16);
    o.y = (unsigned)f2bf(v.z) | ((unsigned)f2bf(v.w) << 16);
    *(uint2*)(dst + off) = o;
}

// ---------------- QKV GEMM: 128x128 tile, 8 waves, 3-slot ring, 1 barrier/step -----
// Wave w: rows (w>>1)*32..+32, cols (w&1)*64..+64. Staging: 1 A-chunk + 1 B-chunk
// per thread; counted vmcnt(2). 3-slot ring removes the trailing barrier: at iter j
// the stage targets slot (j+2)%3 while the slowest wave reads slot j%3 (disjoint).
// Grid 768 = 3 blocks/CU (LDS 48KB). Epilogue: cols<2048 -> bias+RoPE -> qk
// (stride 2048); V region -> bias -> transposed write to vt[bh][hd][s].
__global__ __launch_bounds__(512, 2) void gemm_qkv(const u16* __restrict__ A,
                                                   const u16* __restrict__ Bw,
                                                   const float* __restrict__ bias0,
                                                   const float* __restrict__ bias1,
                                                   const float* __restrict__ bias2,
                                                   const int* __restrict__ days,
                                                   u16* __restrict__ outB,
                                                   u16* __restrict__ vt,
                                                   int M, int N, int K) {
    __shared__ __align__(16) u16 As[3][4096];   // 3 slots of 128x32
    __shared__ __align__(16) u16 Bs[3][4096];
    const int tid = threadIdx.x;
    const int lane = tid & 63;
    const int w = tid >> 6;          // 0..7
    const int wr = w >> 1, wc = w & 1;
    const int lr = lane & 15, lg = lane >> 4;
    const int nbn = N >> 7;          // 24
    const int wgid = (blockIdx.x & 7) * 96 + (blockIdx.x >> 3);  // XCD swizzle, 768=8x96
    const int m0 = (wgid / nbn) << 7;
    const int n0 = (wgid % nbn) << 7;

    f32x4 acc[2][4] = {};

    // staging: chunk cp = w*64+lane in [0,512); row cp>>2, k-col (cp&3)*8
    const int cp = w * 64 + lane;
    const int arow = cp >> 2, kc = (cp & 3) << 3;
    const u16* aptr = A + (size_t)(m0 + arow) * K + kc;
    const u16* bptr = Bw + (size_t)(n0 + arow) * K + kc;
    const int coff = cp * 8;

#define GSTAGE(K0, SLOT)                                                               \
    do {                                                                               \
        __builtin_amdgcn_global_load_lds(                                              \
            (const __attribute__((address_space(1))) void*)(aptr + (K0)),              \
            (__attribute__((address_space(3))) void*)(&As[SLOT][coff]), 16, 0, 0);     \
        __builtin_amdgcn_global_load_lds(                                              \
            (const __attribute__((address_space(1))) void*)(bptr + (K0)),              \
            (__attribute__((address_space(3))) void*)(&Bs[SLOT][coff]), 16, 0, 0);     \
    } while (0)

    const int nks = K >> 5;  // 32 steps of BK=32
    GSTAGE(0, 0);
    int cur = 0, nxt = 1;
    for (int ks = 0; ks < nks; ++ks) {
        if (ks + 1 < nks) {
            GSTAGE((ks + 1) * 32, nxt);
            asm volatile("s_waitcnt vmcnt(2)" ::: "memory");
        } else {
            asm volatile("s_waitcnt vmcnt(0)" ::: "memory");
        }
        __builtin_amdgcn_s_barrier();
        bf16x8 af[2], bfr[4];
#pragma unroll
        for (int i = 0; i < 2; ++i)
            af[i] = *(const bf16x8*)(&As[cur][(wr * 32 + i * 16 + lr) * 32 + lg * 8]);
#pragma unroll
        for (int j = 0; j < 4; ++j)
            bfr[j] = *(const bf16x8*)(&Bs[cur][(wc * 64 + j * 16 + lr) * 32 + lg * 8]);
#pragma unroll
        for (int i = 0; i < 2; ++i)
#pragma unroll
            for (int j = 0; j < 4; ++j)
                acc[i][j] = __builtin_amdgcn_mfma_f32_16x16x32_bf16(af[i], bfr[j],
                                                                    acc[i][j], 0, 0, 0);
        cur = nxt;
        nxt = (nxt == 2) ? 0 : nxt + 1;
    }
#undef GSTAGE

    auto bsel = [&](int ng) -> float {
        return (ng < 1024) ? bias0[ng] : (ng < 2048) ? bias1[ng - 1024] : bias2[ng - 2048];
    };

    if ((n0 + wc * 64) < 2048) {
        // q/k region: wave's 64 cols = one full head; pairs (j, j+2) hold (x1, x2).
        const float C1 = -0.41524101186091903f;  // -log2(10000)/32
        const float inv0 = exp2f((float)lr * C1);
        const float inv1 = exp2f((float)(16 + lr) * C1);
#pragma unroll
        for (int i = 0; i < 2; ++i) {
            int mg = m0 + wr * 32 + i * 16 + lg * 4;
#pragma unroll
            for (int r = 0; r < 4; ++r) {
                int m = mg + r;
                int d = days[m];
                int ad = d < 0 ? -d : d;
                ad = ad > 2047 ? 2047 : ad;
                float pos = (float)ad;
#pragma unroll
                for (int j = 0; j < 2; ++j) {
                    int ng1 = n0 + wc * 64 + j * 16 + lr;
                    int ng2 = ng1 + 32;
                    float x1 = acc[i][j][r] + bsel(ng1);
                    float x2 = acc[i][j + 2][r] + bsel(ng2);
                    float ang = pos * (j ? inv1 : inv0);
                    float sn, cs;
                    __sincosf(ang, &sn, &cs);
                    outB[(size_t)m * 2048 + ng1] = f2bf(x1 * cs - x2 * sn);
                    outB[(size_t)m * 2048 + ng2] = f2bf(x2 * cs + x1 * sn);
                }
            }
        }
    } else {
        // V region: write transposed into vt[bh][hd][s]; 4 consecutive s packed 8B.
        const int h = ((n0 + wc * 64) - 2048) >> 6;
#pragma unroll
        for (int i = 0; i < 2; ++i) {
            int mg = m0 + wr * 32 + i * 16 + lg * 4;
            int b = mg >> 11, s0 = mg & 2047;
#pragma unroll
            for (int j = 0; j < 4; ++j) {
                int hd = j * 16 + lr;
                int ng = 2048 + h * 64 + hd;
                float bias = bsel(ng);
                ushort4 o;
                o.x = f2bf(acc[i][j][0] + bias);
                o.y = f2bf(acc[i][j][1] + bias);
                o.z = f2bf(acc[i][j][2] + bias);
                o.w = f2bf(acc[i][j][3] + bias);
                *(ushort4*)&vt[((size_t)(b * 16 + h) * 64 + hd) * 2048 + s0] = o;
            }
        }
    }
}

// ---------------- out-proj GEMM: split-K, 3-slot ring, 1 barrier/step --------------
__global__ __launch_bounds__(512, 1) void gemm_out(const u16* __restrict__ A,
                                                   const u16* __restrict__ Bw,
                                                   const float* __restrict__ bias0,
                                                   float* __restrict__ outF,
                                                   int M, int N, int K) {
    __shared__ __align__(16) u16 As[2][3][4096];  // [group][slot]
    __shared__ __align__(16) u16 Bs[2][3][4096];
    const int tid = threadIdx.x;
    const int lane = tid & 63;
    const int w4 = (tid >> 6) & 3;
    const int g = tid >> 8;
    const int wr = w4 >> 1, wc = w4 & 1;
    const int lr = lane & 15, lg = lane >> 4;
    const int nbn = N >> 7;
    const int m0 = (blockIdx.x / nbn) << 7;
    const int n0 = (blockIdx.x % nbn) << 7;
    const int kbase = g * (K >> 1);

    f32x4 acc[4][4] = {};

    const u16* aptr[2];
    const u16* bptr[2];
    int ldsoff[2];
#pragma unroll
    for (int i = 0; i < 2; ++i) {
        int c = (w4 * 2 + i) * 64 + lane;
        int row = c >> 2, kc = (c & 3) << 3;
        aptr[i] = A + (size_t)(m0 + row) * K + kbase + kc;
        bptr[i] = Bw + (size_t)(n0 + row) * K + kbase + kc;
        ldsoff[i] = (w4 * 2 + i) * 512;
    }

#define GSTAGE(K0, SLOT)                                                               \
    do {                                                                               \
        _Pragma("unroll") for (int i = 0; i < 2; ++i) {                                \
            __builtin_amdgcn_global_load_lds(                                          \
                (const __attribute__((address_space(1))) void*)(aptr[i] + (K0)),       \
                (__attribute__((address_space(3))) void*)(&As[g][SLOT][ldsoff[i]]),    \
                16, 0, 0);                                                             \
            __builtin_amdgcn_global_load_lds(                                          \
                (const __attribute__((address_space(1))) void*)(bptr[i] + (K0)),       \
                (__attribute__((address_space(3))) void*)(&Bs[g][SLOT][ldsoff[i]]),    \
                16, 0, 0);                                                             \
        }                                                                              \
    } while (0)

    const int nks = K >> 6;  // per-group steps = 16
    GSTAGE(0, 0);
    int cur = 0, nxt = 1;
    for (int ks = 0; ks < nks; ++ks) {
        if (ks + 1 < nks) {
            GSTAGE((ks + 1) * 32, nxt);
            asm volatile("s_waitcnt vmcnt(4)" ::: "memory");
        } else {
            asm volatile("s_waitcnt vmcnt(0)" ::: "memory");
        }
        __builtin_amdgcn_s_barrier();
        bf16x8 af[4], bfr[4];
#pragma unroll
        for (int i = 0; i < 4; ++i)
            af[i] = *(const bf16x8*)(&As[g][cur][(wr * 64 + i * 16 + lr) * 32 + lg * 8]);
#pragma unroll
        for (int j = 0; j < 4; ++j)
            bfr[j] = *(const bf16x8*)(&Bs[g][cur][(wc * 64 + j * 16 + lr) * 32 + lg * 8]);
#pragma unroll
        for (int i = 0; i < 4; ++i)
#pragma unroll
            for (int j = 0; j < 4; ++j)
                acc[i][j] = __builtin_amdgcn_mfma_f32_16x16x32_bf16(af[i], bfr[j],
                                                                    acc[i][j], 0, 0, 0);
        cur = nxt;
        nxt = (nxt == 2) ? 0 : nxt + 1;
    }
#undef GSTAGE

    float* xch = (float*)&As[0][0][0];
    const int t256 = tid & 255;
#pragma unroll
    for (int hf = 0; hf < 2; ++hf) {
        __syncthreads();
        if (g == 1) {
#pragma unroll
            for (int i = 0; i < 2; ++i)
#pragma unroll
                for (int j = 0; j < 4; ++j)
                    *(f32x4*)&xch[((t256 * 8) + i * 4 + j) * 4] = acc[hf * 2 + i][j];
        }
        __syncthreads();
        if (g == 0) {
#pragma unroll
            for (int i = 0; i < 2; ++i)
#pragma unroll
                for (int j = 0; j < 4; ++j)
                    acc[hf * 2 + i][j] += *(const f32x4*)&xch[((t256 * 8) + i * 4 + j) * 4];
        }
    }
    if (g == 0) {
#pragma unroll
        for (int i = 0; i < 4; ++i) {
            int mg = m0 + wr * 64 + i * 16 + lg * 4;
#pragma unroll
            for (int j = 0; j < 4; ++j) {
                int ng = n0 + wc * 64 + j * 16 + lr;
                float bias = bias0[ng];
#pragma unroll
                for (int r = 0; r < 4; ++r)
                    outF[(size_t)(mg + r) * N + ng] = acc[i][j][r] + bias;
            }
        }
    }
}

// ---------------- V prefix sums over k-tiles: VPS[bh][t][d], t in [0,32] -----------
__global__ __launch_bounds__(256) void vps_k(const u16* __restrict__ vt,
                                             float* __restrict__ vps) {
    __shared__ float ts[32][32];
    const int bh = blockIdx.x >> 1;
    const int d0 = (blockIdx.x & 1) * 32;
    const int dl = threadIdx.x >> 3;
    const int seg = threadIdx.x & 7;
    const u16* vrow = vt + ((size_t)bh * 64 + d0 + dl) * 2048 + seg * 256;
#pragma unroll
    for (int tt = 0; tt < 4; ++tt) {
        float s = 0.f;
#pragma unroll
        for (int i = 0; i < 8; ++i) {
            bf16x8 v = *(const bf16x8*)(vrow + tt * 64 + i * 8);
#pragma unroll
            for (int e = 0; e < 8; ++e) s += bf2f((u16)v[e]);
        }
        ts[dl][seg * 4 + tt] = s;
    }
    __syncthreads();
    if (threadIdx.x < 32) {
        int d = threadIdx.x;
        float acc = 0.f;
        for (int t = 0; t <= 32; ++t) {
            vps[((size_t)bh * 33 + t) * 64 + d0 + d] = acc;
            if (t < 32) acc += ts[d][t];
        }
    }
}

// ---------------- flash attention v9 -----------------------------------------------
__device__ __forceinline__ void attn_tile(const u16* __restrict__ Ks,
                                          const u16* __restrict__ Vs,
                                          u16* __restrict__ Pw,
                                          const int* __restrict__ dbk,
                                          float dkmax_c, bf16x8 pconst, float pcr,
                                          bf16x8 bq0, bf16x8 bq1, float dq_c, float c1,
                                          int qrel, bool domask,
                                          float& l_part, f32x4* acc, int lr, int lg) {
    if (!domask && __all(dkmax_c - dq_c < -20.0f)) {
        l_part += 16.0f * pcr;
        __builtin_amdgcn_s_setprio(1);
#pragma unroll
        for (int pv = 0; pv < 2; ++pv) {
            int chunk = pv * 4 + lg;
#pragma unroll
            for (int c = 0; c < 4; ++c) {
                const int r3 = c * 16 + lr;
                bf16x8 bv = *(const bf16x8*)(Vs + r3 * 64 + ((chunk ^ (r3 & 7)) << 3));
                acc[c] = __builtin_amdgcn_mfma_f32_16x16x32_bf16(pconst, bv, acc[c], 0, 0, 0);
            }
        }
        __builtin_amdgcn_s_setprio(0);
        return;
    }
    f32x4 st_acc[4];
    __builtin_amdgcn_s_setprio(1);
#pragma unroll
    for (int st = 0; st < 4; ++st) {
        const int r2 = st * 16 + lr;
        const u16* kr = Ks + r2 * 64;
        bf16x8 ka0 = *(const bf16x8*)(kr + ((lg ^ (r2 & 7)) << 3));
        bf16x8 ka1 = *(const bf16x8*)(kr + (((4 + lg) ^ (r2 & 7)) << 3));
        f32x4 t = {};
        t = __builtin_amdgcn_mfma_f32_16x16x32_bf16(ka0, bq0, t, 0, 0, 0);
        t = __builtin_amdgcn_mfma_f32_16x16x32_bf16(ka1, bq1, t, 0, 0, 0);
        st_acc[st] = t;
    }
    __builtin_amdgcn_s_setprio(0);
    const float L2E = 1.4426950408889634f;
    const float POFF = 17.312340490667562f;  // 12*log2(e)
    float p[4][4];
#pragma unroll
    for (int st = 0; st < 4; ++st) {
        int4 dk4 = *(const int4*)(dbk + st * 16 + lg * 4);
#pragma unroll
        for (int r = 0; r < 4; ++r) {
            float dkf = (float)((&dk4.x)[r]);
            float dec = exp2f(__builtin_fmaf(dkf, c1, -dq_c));  // decay/8
            float v = st_acc[st][r] * dec;
            p[st][r] = exp2f(__builtin_fmaf(v, L2E, -POFF));
        }
    }
    if (domask) {
#pragma unroll
        for (int st = 0; st < 4; ++st)
#pragma unroll
            for (int r = 0; r < 4; ++r)
                p[st][r] = (st * 16 + lg * 4 + r <= qrel) ? p[st][r] : 0.f;
    }
#pragma unroll
    for (int st = 0; st < 4; ++st)
#pragma unroll
        for (int r = 0; r < 4; ++r) l_part += p[st][r];
#pragma unroll
    for (int st = 0; st < 4; ++st) {
        unsigned lo, hi;
        asm("v_cvt_pk_bf16_f32 %0, %1, %2" : "=v"(lo) : "v"(p[st][0]), "v"(p[st][1]));
        asm("v_cvt_pk_bf16_f32 %0, %1, %2" : "=v"(hi) : "v"(p[st][2]), "v"(p[st][3]));
        uint2 pk;
        pk.x = lo;
        pk.y = hi;
        int chunk = st * 2 + (lg >> 1);
        int idx = lr * 64 + ((chunk ^ (lr & 7)) << 3) + ((lg & 1) << 2);
        *(uint2*)&Pw[idx] = pk;
    }
    __builtin_amdgcn_s_setprio(1);
#pragma unroll
    for (int pv = 0; pv < 2; ++pv) {
        int chunk = pv * 4 + lg;
        bf16x8 pa = *(const bf16x8*)&Pw[lr * 64 + ((chunk ^ (lr & 7)) << 3)];
#pragma unroll
        for (int c = 0; c < 4; ++c) {
            const int r3 = c * 16 + lr;
            bf16x8 bv = *(const bf16x8*)(Vs + r3 * 64 + ((chunk ^ (r3 & 7)) << 3));
            acc[c] = __builtin_amdgcn_mfma_f32_16x16x32_bf16(pa, bv, acc[c], 0, 0, 0);
        }
    }
    __builtin_amdgcn_s_setprio(0);
}

__global__ __launch_bounds__(256, 4) void attn_k(const u16* __restrict__ qkv,
                                                 const u16* __restrict__ vt,
                                                 const int* __restrict__ days,
                                                 const float* __restrict__ decay_p,
                                                 const float* __restrict__ vps,
                                                 u16* __restrict__ attn_out) {
    __shared__ __align__(16) u16 Ks[2][4096];
    __shared__ __align__(16) u16 Vs[2][4096];
    __shared__ __align__(16) u16 Plds[4][1024];
    const int tid = threadIdx.x;
    const int lane = tid & 63;
    const int w = tid >> 6;
    const int lr = lane & 15, lg = lane >> 4;
    const int wg = (blockIdx.x & 7) * 128 + (blockIdx.x >> 3);
    const int qt = wg & 31;
    const int bh = wg >> 5;
    const int b = bh >> 4, h = bh & 15;
    const int qb = qt * 64 + w * 16;
    const float rate = decay_p[0];
    const float c1 = rate * 1.4426950408889634f;

    // q|k buffer: rows [4096], stride 2048 (q cols 0..1023, k cols 1024..2047)
    const u16* qmat = qkv + (size_t)b * 2048 * 2048 + h * 64;
    const u16* kmat = qmat + 1024;
    const u16* vtm = vt + (size_t)bh * 64 * 2048;
    const int* db = days + b * 2048;

    const int cp0 = (w * 2 + 0) * 64 + lane;
    const int cp1 = (w * 2 + 1) * 64 + lane;
    const int r0 = cp0 >> 3, c0 = cp0 & 7;
    const int r1 = cp1 >> 3, c1i = cp1 & 7;
    const u16* ksrc0 = kmat + (size_t)r0 * 2048 + ((c0 ^ (r0 & 7)) << 3);
    const u16* ksrc1 = kmat + (size_t)r1 * 2048 + ((c1i ^ (r1 & 7)) << 3);
    const u16* vsrc0 = vtm + (size_t)r0 * 2048 + ((c0 ^ (r0 & 7)) << 3);
    const u16* vsrc1 = vtm + (size_t)r1 * 2048 + ((c1i ^ (r1 & 7)) << 3);
    const int doff0 = (w * 2 + 0) * 512;
    const int doff1 = (w * 2 + 1) * 512;

#define STAGE(T, SLOT)                                                                 \
    do {                                                                               \
        __builtin_amdgcn_global_load_lds(                                              \
            (const __attribute__((address_space(1))) void*)(ksrc0 +                    \
                                                            (size_t)(T) * 64 * 2048), \
            (__attribute__((address_space(3))) void*)(&Ks[SLOT][doff0]), 16, 0, 0);    \
        __builtin_amdgcn_global_load_lds(                                              \
            (const __attribute__((address_space(1))) void*)(ksrc1 +                    \
                                                            (size_t)(T) * 64 * 2048), \
            (__attribute__((address_space(3))) void*)(&Ks[SLOT][doff1]), 16, 0, 0);    \
        __builtin_amdgcn_global_load_lds(                                              \
            (const __attribute__((address_space(1))) void*)(vsrc0 + (size_t)(T) * 64), \
            (__attribute__((address_space(3))) void*)(&Vs[SLOT][doff0]), 16, 0, 0);    \
        __builtin_amdgcn_global_load_lds(                                              \
            (const __attribute__((address_space(1))) void*)(vsrc1 + (size_t)(T) * 64), \
            (__attribute__((address_space(3))) void*)(&Vs[SLOT][doff1]), 16, 0, 0);    \
    } while (0)

    const float dq00_c = (float)db[qt * 64] * c1 + 3.0f;
    int t0;
    {
        const int l32 = lane & 31;
        float dm = (float)db[l32 * 64 + 63] * c1;
        bool cnd = (lane < qt) && (dm < dq00_c - 20.0f);
        unsigned long long m = __ballot(cnd);
        t0 = (int)__builtin_ctzll(~m);
    }

    STAGE(t0, 0);

    bf16x8 bq0, bq1;
    {
        const u16* qp = qmat + (size_t)(qb + lr) * 2048 + lg * 8;
        bq0 = *(const bf16x8*)qp;
        bq1 = *(const bf16x8*)(qp + 32);
    }
    const float dq_c = (float)db[qb + lr] * c1 + 3.0f;

    const u16 pcu = f2bf(exp2f(-17.312340490667562f));
    const float pcr = bf2f(pcu);
    bf16x8 pconst;
#pragma unroll
    for (int i = 0; i < 8; ++i) pconst[i] = (short)pcu;

    float lp = (float)t0 * 16.0f * pcr;
    f32x4 acc[4];
#pragma unroll
    for (int c = 0; c < 4; ++c) {
        float vv = pcr * vps[((size_t)bh * 33 + t0) * 64 + c * 16 + lr];
        acc[c] = (f32x4){vv, vv, vv, vv};
    }

    for (int kt = t0; kt <= qt; ++kt) {
        const int cur = (kt - t0) & 1;
        if (kt < qt) {
            STAGE(kt + 1, cur ^ 1);
            asm volatile("s_waitcnt vmcnt(4)" ::: "memory");
        } else {
            asm volatile("s_waitcnt vmcnt(0)" ::: "memory");
        }
        __builtin_amdgcn_s_barrier();
        const int* dbk = days + b * 2048 + kt * 64;
        const float dkmax_c = (float)dbk[63] * c1;
        attn_tile(Ks[cur], Vs[cur], Plds[w], dbk, dkmax_c, pconst, pcr,
                  bq0, bq1, dq_c, c1, w * 16 + lr, kt == qt, lp, acc, lr, lg);
        __builtin_amdgcn_s_barrier();
    }
#undef STAGE

    float l_full = lp + __shfl_xor(lp, 16);
    l_full += __shfl_xor(l_full, 32);
    float inv_[4];
#pragma unroll
    for (int r = 0; r < 4; ++r) inv_[r] = 1.0f / __shfl(l_full, lg * 4 + r);
#pragma unroll
    for (int c = 0; c < 4; ++c)
#pragma unroll
        for (int r = 0; r < 4; ++r) {
            const int qg = qb + lg * 4 + r;
            attn_out[(size_t)(b * 2048 + qg) * 1024 + h * 64 + c * 16 + lr] =
                f2bf(acc[c][r] * inv_[r]);
        }
}

// ---------------- launch -----------------------------------------------------------
extern "C" void kernel_launch(void* const* d_in, const int* in_sizes, int n_in,
                              void* d_out, int out_size, void* d_ws, size_t ws_size,
                              hipStream_t stream) {
    const float* x = (const float*)d_in[0];
    const float* Wq = (const float*)d_in[1];
    const float* bq = (const float*)d_in[2];
    const float* Wk = (const float*)d_in[3];
    const float* bk = (const float*)d_in[4];
    const float* Wv = (const float*)d_in[5];
    const float* bv = (const float*)d_in[6];
    const float* Wo = (const float*)d_in[7];
    const float* bo = (const float*)d_in[8];
    const float* decay = (const float*)d_in[9];
    const int* days = (const int*)d_in[11];
    float* out = (float*)d_out;

    char* ws = (char*)d_ws;
    u16* xb = (u16*)(ws);                   //  8 MB: x bf16 [4096][1024]
    u16* wqkv = (u16*)(ws + 8388608);       //  6 MB: [Wq;Wk;Wv] bf16 [3072][1024]
    u16* wo = (u16*)(ws + 14680064);        //  2 MB: Wo bf16 [1024][1024]
    u16* qkb = (u16*)(ws + 16777216);       // 16 MB: q|k bf16 [4096][2048]
    u16* vtb = (u16*)(ws + 41943040);       //  8 MB: Vt bf16 [32][64][2048]
    u16* attb = (u16*)(ws + 50331648);      //  8 MB: attn out bf16 [4096][1024]
    float* vpsb = (float*)(ws + 58720256);  // 270 KB: V prefix sums [32][33][64] f32

    convert_all_k<<<8192, 256, 0, stream>>>(x, Wq, Wk, Wv, Wo, xb, wqkv, wo);

    gemm_qkv<<<768, 512, 0, stream>>>(xb, wqkv, bq, bk, bv, days, qkb, vtb, 4096,
                                      3072, 1024);
    vps_k<<<64, 256, 0, stream>>>(vtb, vpsb);
    attn_k<<<1024, 256, 0, stream>>>(qkb, vtb, days, decay, vpsb, attb);
    gemm_out<<<256, 512, 0, stream>>>(attb, wo, bo, out, 4096, 1024, 1024);
}

// Round 23
// 96.161 us; speedup vs baseline: 1.0663x; 1.0052x over previous
//
#include <hip/hip_runtime.h>
#include <hip/hip_bf16.h>

// B=2, S=2048, D=1024, H=16, HD=64. fp32 in, fp32 out, bf16-tolerance threshold.
// Pipeline: convert->bf16 | edk precompute | QKV GEMM (128x128, 8 waves, 3-slot
//           ring; fused bias+RoPE; V transposed to Vt) | V-prefix-sum |
//           flash attn v10 (far via VPS; factored decay: dec = edk * eqt) |
//           out GEMM (split-K).

typedef unsigned short u16;
typedef short bf16x8 __attribute__((ext_vector_type(8)));
typedef float f32x4 __attribute__((ext_vector_type(4)));

__device__ __forceinline__ u16 f2bf(float f) {
    unsigned u = __builtin_bit_cast(unsigned, f);
    u += 0x7fffu + ((u >> 16) & 1u);   // RNE
    return (u16)(u >> 16);
}
__device__ __forceinline__ float bf2f(u16 h) {
    unsigned u = ((unsigned)h) << 16;
    return __builtin_bit_cast(float, u);
}

// ---------------- fused fp32 -> bf16 convert for all 5 tensors ---------------------
__global__ __launch_bounds__(256) void convert_all_k(const float* __restrict__ x,
                                                     const float* __restrict__ wq,
                                                     const float* __restrict__ wk,
                                                     const float* __restrict__ wv,
                                                     const float* __restrict__ wo_,
                                                     u16* __restrict__ xb,
                                                     u16* __restrict__ wqkv,
                                                     u16* __restrict__ wob) {
    int i = (blockIdx.x * 256 + threadIdx.x) * 4;
    const float* src;
    u16* dst;
    int off;
    if (i < 4194304) {
        src = x; dst = xb; off = i;
    } else if (i < 5242880) {
        src = wq; dst = wqkv; off = i - 4194304;
    } else if (i < 6291456) {
        src = wk; dst = wqkv + 1048576; off = i - 5242880;
    } else if (i < 7340032) {
        src = wv; dst = wqkv + 2097152; off = i - 6291456;
    } else {
        src = wo_; dst = wob; off = i - 7340032;
    }
    float4 v = *(const float4*)(src + off);
    uint2 o;
    o.x = (unsigned)f2bf(v.x) | ((unsigned)f2bf(v.y) << 16);
    o.y = (unsigned)f2bf(v.z) | ((unsigned)f2bf(v.w) << 16);
    *(uint2*)(dst + off) = o;
}

// ---------------- edk precompute: edk[i] = exp2((days[i]-tilemax)*c1) --------------
// tmaxc[b*32+t] = tilemax*c1 (c1 = rate*log2e). Within-tile span keeps edk >= ~2^-22;
// cross-tile magnitudes never mix (each tile uses its own tilemax).
__global__ __launch_bounds__(256) void edk_k(const int* __restrict__ days,
                                             const float* __restrict__ decay_p,
                                             float* __restrict__ edk,
                                             float* __restrict__ tmaxc) {
    int i = blockIdx.x * 256 + threadIdx.x;  // 4096 total
    const float c1 = decay_p[0] * 1.4426950408889634f;
    int b = i >> 11, r = i & 2047;
    int tile = r >> 6;
    int tmax = days[(b << 11) + (tile << 6) + 63];
    edk[i] = exp2f((float)(days[i] - tmax) * c1);
    if ((r & 63) == 63) tmaxc[b * 32 + tile] = (float)tmax * c1;
}

// ---------------- QKV GEMM: 128x128 tile, 8 waves, 3-slot ring, 1 barrier/step -----
__global__ __launch_bounds__(512, 2) void gemm_qkv(const u16* __restrict__ A,
                                                   const u16* __restrict__ Bw,
                                                   const float* __restrict__ bias0,
                                                   const float* __restrict__ bias1,
                                                   const float* __restrict__ bias2,
                                                   const int* __restrict__ days,
                                                   u16* __restrict__ outB,
                                                   u16* __restrict__ vt,
                                                   int M, int N, int K) {
    __shared__ __align__(16) u16 As[3][4096];   // 3 slots of 128x32
    __shared__ __align__(16) u16 Bs[3][4096];
    const int tid = threadIdx.x;
    const int lane = tid & 63;
    const int w = tid >> 6;          // 0..7
    const int wr = w >> 1, wc = w & 1;
    const int lr = lane & 15, lg = lane >> 4;
    const int nbn = N >> 7;          // 24
    const int wgid = (blockIdx.x & 7) * 96 + (blockIdx.x >> 3);  // XCD swizzle, 768=8x96
    const int m0 = (wgid / nbn) << 7;
    const int n0 = (wgid % nbn) << 7;

    f32x4 acc[2][4] = {};

    const int cp = w * 64 + lane;
    const int arow = cp >> 2, kc = (cp & 3) << 3;
    const u16* aptr = A + (size_t)(m0 + arow) * K + kc;
    const u16* bptr = Bw + (size_t)(n0 + arow) * K + kc;
    const int coff = cp * 8;

#define GSTAGE(K0, SLOT)                                                               \
    do {                                                                               \
        __builtin_amdgcn_global_load_lds(                                              \
            (const __attribute__((address_space(1))) void*)(aptr + (K0)),              \
            (__attribute__((address_space(3))) void*)(&As[SLOT][coff]), 16, 0, 0);     \
        __builtin_amdgcn_global_load_lds(                                              \
            (const __attribute__((address_space(1))) void*)(bptr + (K0)),              \
            (__attribute__((address_space(3))) void*)(&Bs[SLOT][coff]), 16, 0, 0);     \
    } while (0)

    const int nks = K >> 5;  // 32 steps of BK=32
    GSTAGE(0, 0);
    int cur = 0, nxt = 1;
    for (int ks = 0; ks < nks; ++ks) {
        if (ks + 1 < nks) {
            GSTAGE((ks + 1) * 32, nxt);
            asm volatile("s_waitcnt vmcnt(2)" ::: "memory");
        } else {
            asm volatile("s_waitcnt vmcnt(0)" ::: "memory");
        }
        __builtin_amdgcn_s_barrier();
        bf16x8 af[2], bfr[4];
#pragma unroll
        for (int i = 0; i < 2; ++i)
            af[i] = *(const bf16x8*)(&As[cur][(wr * 32 + i * 16 + lr) * 32 + lg * 8]);
#pragma unroll
        for (int j = 0; j < 4; ++j)
            bfr[j] = *(const bf16x8*)(&Bs[cur][(wc * 64 + j * 16 + lr) * 32 + lg * 8]);
#pragma unroll
        for (int i = 0; i < 2; ++i)
#pragma unroll
            for (int j = 0; j < 4; ++j)
                acc[i][j] = __builtin_amdgcn_mfma_f32_16x16x32_bf16(af[i], bfr[j],
                                                                    acc[i][j], 0, 0, 0);
        cur = nxt;
        nxt = (nxt == 2) ? 0 : nxt + 1;
    }
#undef GSTAGE

    auto bsel = [&](int ng) -> float {
        return (ng < 1024) ? bias0[ng] : (ng < 2048) ? bias1[ng - 1024] : bias2[ng - 2048];
    };

    if ((n0 + wc * 64) < 2048) {
        // q/k region: wave's 64 cols = one full head; pairs (j, j+2) hold (x1, x2).
        const float C1 = -0.41524101186091903f;  // -log2(10000)/32
        const float inv0 = exp2f((float)lr * C1);
        const float inv1 = exp2f((float)(16 + lr) * C1);
#pragma unroll
        for (int i = 0; i < 2; ++i) {
            int mg = m0 + wr * 32 + i * 16 + lg * 4;
#pragma unroll
            for (int r = 0; r < 4; ++r) {
                int m = mg + r;
                int d = days[m];
                int ad = d < 0 ? -d : d;
                ad = ad > 2047 ? 2047 : ad;
                float pos = (float)ad;
#pragma unroll
                for (int j = 0; j < 2; ++j) {
                    int ng1 = n0 + wc * 64 + j * 16 + lr;
                    int ng2 = ng1 + 32;
                    float x1 = acc[i][j][r] + bsel(ng1);
                    float x2 = acc[i][j + 2][r] + bsel(ng2);
                    float ang = pos * (j ? inv1 : inv0);
                    float sn, cs;
                    __sincosf(ang, &sn, &cs);
                    outB[(size_t)m * 2048 + ng1] = f2bf(x1 * cs - x2 * sn);
                    outB[(size_t)m * 2048 + ng2] = f2bf(x2 * cs + x1 * sn);
                }
            }
        }
    } else {
        // V region: write transposed into vt[bh][hd][s]; 4 consecutive s packed 8B.
        const int h = ((n0 + wc * 64) - 2048) >> 6;
#pragma unroll
        for (int i = 0; i < 2; ++i) {
            int mg = m0 + wr * 32 + i * 16 + lg * 4;
            int b = mg >> 11, s0 = mg & 2047;
#pragma unroll
            for (int j = 0; j < 4; ++j) {
                int hd = j * 16 + lr;
                int ng = 2048 + h * 64 + hd;
                float bias = bsel(ng);
                ushort4 o;
                o.x = f2bf(acc[i][j][0] + bias);
                o.y = f2bf(acc[i][j][1] + bias);
                o.z = f2bf(acc[i][j][2] + bias);
                o.w = f2bf(acc[i][j][3] + bias);
                *(ushort4*)&vt[((size_t)(b * 16 + h) * 64 + hd) * 2048 + s0] = o;
            }
        }
    }
}

// ---------------- out-proj GEMM: split-K, 3-slot ring, 1 barrier/step --------------
__global__ __launch_bounds__(512, 1) void gemm_out(const u16* __restrict__ A,
                                                   const u16* __restrict__ Bw,
                                                   const float* __restrict__ bias0,
                                                   float* __restrict__ outF,
                                                   int M, int N, int K) {
    __shared__ __align__(16) u16 As[2][3][4096];  // [group][slot]
    __shared__ __align__(16) u16 Bs[2][3][4096];
    const int tid = threadIdx.x;
    const int lane = tid & 63;
    const int w4 = (tid >> 6) & 3;
    const int g = tid >> 8;
    const int wr = w4 >> 1, wc = w4 & 1;
    const int lr = lane & 15, lg = lane >> 4;
    const int nbn = N >> 7;
    const int m0 = (blockIdx.x / nbn) << 7;
    const int n0 = (blockIdx.x % nbn) << 7;
    const int kbase = g * (K >> 1);

    f32x4 acc[4][4] = {};

    const u16* aptr[2];
    const u16* bptr[2];
    int ldsoff[2];
#pragma unroll
    for (int i = 0; i < 2; ++i) {
        int c = (w4 * 2 + i) * 64 + lane;
        int row = c >> 2, kc = (c & 3) << 3;
        aptr[i] = A + (size_t)(m0 + row) * K + kbase + kc;
        bptr[i] = Bw + (size_t)(n0 + row) * K + kbase + kc;
        ldsoff[i] = (w4 * 2 + i) * 512;
    }

#define GSTAGE(K0, SLOT)                                                               \
    do {                                                                               \
        _Pragma("unroll") for (int i = 0; i < 2; ++i) {                                \
            __builtin_amdgcn_global_load_lds(                                          \
                (const __attribute__((address_space(1))) void*)(aptr[i] + (K0)),       \
                (__attribute__((address_space(3))) void*)(&As[g][SLOT][ldsoff[i]]),    \
                16, 0, 0);                                                             \
            __builtin_amdgcn_global_load_lds(                                          \
                (const __attribute__((address_space(1))) void*)(bptr[i] + (K0)),       \
                (__attribute__((address_space(3))) void*)(&Bs[g][SLOT][ldsoff[i]]),    \
                16, 0, 0);                                                             \
        }                                                                              \
    } while (0)

    const int nks = K >> 6;  // per-group steps = 16
    GSTAGE(0, 0);
    int cur = 0, nxt = 1;
    for (int ks = 0; ks < nks; ++ks) {
        if (ks + 1 < nks) {
            GSTAGE((ks + 1) * 32, nxt);
            asm volatile("s_waitcnt vmcnt(4)" ::: "memory");
        } else {
            asm volatile("s_waitcnt vmcnt(0)" ::: "memory");
        }
        __builtin_amdgcn_s_barrier();
        bf16x8 af[4], bfr[4];
#pragma unroll
        for (int i = 0; i < 4; ++i)
            af[i] = *(const bf16x8*)(&As[g][cur][(wr * 64 + i * 16 + lr) * 32 + lg * 8]);
#pragma unroll
        for (int j = 0; j < 4; ++j)
            bfr[j] = *(const bf16x8*)(&Bs[g][cur][(wc * 64 + j * 16 + lr) * 32 + lg * 8]);
#pragma unroll
        for (int i = 0; i < 4; ++i)
#pragma unroll
            for (int j = 0; j < 4; ++j)
                acc[i][j] = __builtin_amdgcn_mfma_f32_16x16x32_bf16(af[i], bfr[j],
                                                                    acc[i][j], 0, 0, 0);
        cur = nxt;
        nxt = (nxt == 2) ? 0 : nxt + 1;
    }
#undef GSTAGE

    float* xch = (float*)&As[0][0][0];
    const int t256 = tid & 255;
#pragma unroll
    for (int hf = 0; hf < 2; ++hf) {
        __syncthreads();
        if (g == 1) {
#pragma unroll
            for (int i = 0; i < 2; ++i)
#pragma unroll
                for (int j = 0; j < 4; ++j)
                    *(f32x4*)&xch[((t256 * 8) + i * 4 + j) * 4] = acc[hf * 2 + i][j];
        }
        __syncthreads();
        if (g == 0) {
#pragma unroll
            for (int i = 0; i < 2; ++i)
#pragma unroll
                for (int j = 0; j < 4; ++j)
                    acc[hf * 2 + i][j] += *(const f32x4*)&xch[((t256 * 8) + i * 4 + j) * 4];
        }
    }
    if (g == 0) {
#pragma unroll
        for (int i = 0; i < 4; ++i) {
            int mg = m0 + wr * 64 + i * 16 + lg * 4;
#pragma unroll
            for (int j = 0; j < 4; ++j) {
                int ng = n0 + wc * 64 + j * 16 + lr;
                float bias = bias0[ng];
#pragma unroll
                for (int r = 0; r < 4; ++r)
                    outF[(size_t)(mg + r) * N + ng] = acc[i][j][r] + bias;
            }
        }
    }
}

// ---------------- V prefix sums over k-tiles: VPS[bh][t][d], t in [0,32] -----------
__global__ __launch_bounds__(256) void vps_k(const u16* __restrict__ vt,
                                             float* __restrict__ vps) {
    __shared__ float ts[32][32];
    const int bh = blockIdx.x >> 1;
    const int d0 = (blockIdx.x & 1) * 32;
    const int dl = threadIdx.x >> 3;
    const int seg = threadIdx.x & 7;
    const u16* vrow = vt + ((size_t)bh * 64 + d0 + dl) * 2048 + seg * 256;
#pragma unroll
    for (int tt = 0; tt < 4; ++tt) {
        float s = 0.f;
#pragma unroll
        for (int i = 0; i < 8; ++i) {
            bf16x8 v = *(const bf16x8*)(vrow + tt * 64 + i * 8);
#pragma unroll
            for (int e = 0; e < 8; ++e) s += bf2f((u16)v[e]);
        }
        ts[dl][seg * 4 + tt] = s;
    }
    __syncthreads();
    if (threadIdx.x < 32) {
        int d = threadIdx.x;
        float acc = 0.f;
        for (int t = 0; t <= 32; ++t) {
            vps[((size_t)bh * 33 + t) * 64 + d0 + d] = acc;
            if (t < 32) acc += ts[d][t];
        }
    }
}

// ---------------- flash attention v10 ----------------------------------------------
// Factored decay: dec = edk[k] * eqt where edk = exp2((dk - tilemax)*c1) is
// precomputed per key and eqt = exp2(tilemax*c1 - dq_c) is one exp2 per lane per
// tile. Exact path: 1 load + 1 mul per element replaces cvt+fma+exp2.
__device__ __forceinline__ void attn_tile(const u16* __restrict__ Ks,
                                          const u16* __restrict__ Vs,
                                          u16* __restrict__ Pw,
                                          const float* __restrict__ ebk, float eqt,
                                          float dkmax_c, bf16x8 pconst, float pcr,
                                          bf16x8 bq0, bf16x8 bq1, float dq_c,
                                          int qrel, bool domask,
                                          float& l_part, f32x4* acc, int lr, int lg) {
    if (!domask && __all(dkmax_c - dq_c < -20.0f)) {
        l_part += 16.0f * pcr;
        __builtin_amdgcn_s_setprio(1);
#pragma unroll
        for (int pv = 0; pv < 2; ++pv) {
            int chunk = pv * 4 + lg;
#pragma unroll
            for (int c = 0; c < 4; ++c) {
                const int r3 = c * 16 + lr;
                bf16x8 bv = *(const bf16x8*)(Vs + r3 * 64 + ((chunk ^ (r3 & 7)) << 3));
                acc[c] = __builtin_amdgcn_mfma_f32_16x16x32_bf16(pconst, bv, acc[c], 0, 0, 0);
            }
        }
        __builtin_amdgcn_s_setprio(0);
        return;
    }
    f32x4 st_acc[4];
    __builtin_amdgcn_s_setprio(1);
#pragma unroll
    for (int st = 0; st < 4; ++st) {
        const int r2 = st * 16 + lr;
        const u16* kr = Ks + r2 * 64;
        bf16x8 ka0 = *(const bf16x8*)(kr + ((lg ^ (r2 & 7)) << 3));
        bf16x8 ka1 = *(const bf16x8*)(kr + (((4 + lg) ^ (r2 & 7)) << 3));
        f32x4 t = {};
        t = __builtin_amdgcn_mfma_f32_16x16x32_bf16(ka0, bq0, t, 0, 0, 0);
        t = __builtin_amdgcn_mfma_f32_16x16x32_bf16(ka1, bq1, t, 0, 0, 0);
        st_acc[st] = t;
    }
    __builtin_amdgcn_s_setprio(0);
    const float L2E = 1.4426950408889634f;
    const float POFF = 17.312340490667562f;  // 12*log2(e)
    float p[4][4];
#pragma unroll
    for (int st = 0; st < 4; ++st) {
        float4 ek4 = *(const float4*)(ebk + st * 16 + lg * 4);
#pragma unroll
        for (int r = 0; r < 4; ++r) {
            float dec = (&ek4.x)[r] * eqt;  // = exp2(dk*c1 - dq_c), includes /8
            float v = st_acc[st][r] * dec;
            p[st][r] = exp2f(__builtin_fmaf(v, L2E, -POFF));
        }
    }
    if (domask) {
#pragma unroll
        for (int st = 0; st < 4; ++st)
#pragma unroll
            for (int r = 0; r < 4; ++r)
                p[st][r] = (st * 16 + lg * 4 + r <= qrel) ? p[st][r] : 0.f;
    }
#pragma unroll
    for (int st = 0; st < 4; ++st)
#pragma unroll
        for (int r = 0; r < 4; ++r) l_part += p[st][r];
#pragma unroll
    for (int st = 0; st < 4; ++st) {
        unsigned lo, hi;
        asm("v_cvt_pk_bf16_f32 %0, %1, %2" : "=v"(lo) : "v"(p[st][0]), "v"(p[st][1]));
        asm("v_cvt_pk_bf16_f32 %0, %1, %2" : "=v"(hi) : "v"(p[st][2]), "v"(p[st][3]));
        uint2 pk;
        pk.x = lo;
        pk.y = hi;
        int chunk = st * 2 + (lg >> 1);
        int idx = lr * 64 + ((chunk ^ (lr & 7)) << 3) + ((lg & 1) << 2);
        *(uint2*)&Pw[idx] = pk;
    }
    __builtin_amdgcn_s_setprio(1);
#pragma unroll
    for (int pv = 0; pv < 2; ++pv) {
        int chunk = pv * 4 + lg;
        bf16x8 pa = *(const bf16x8*)&Pw[lr * 64 + ((chunk ^ (lr & 7)) << 3)];
#pragma unroll
        for (int c = 0; c < 4; ++c) {
            const int r3 = c * 16 + lr;
            bf16x8 bv = *(const bf16x8*)(Vs + r3 * 64 + ((chunk ^ (r3 & 7)) << 3));
            acc[c] = __builtin_amdgcn_mfma_f32_16x16x32_bf16(pa, bv, acc[c], 0, 0, 0);
        }
    }
    __builtin_amdgcn_s_setprio(0);
}

__global__ __launch_bounds__(256, 4) void attn_k(const u16* __restrict__ qkv,
                                                 const u16* __restrict__ vt,
                                                 const int* __restrict__ days,
                                                 const float* __restrict__ decay_p,
                                                 const float* __restrict__ vps,
                                                 const float* __restrict__ edk,
                                                 const float* __restrict__ tmaxc,
                                                 u16* __restrict__ attn_out) {
    __shared__ __align__(16) u16 Ks[2][4096];
    __shared__ __align__(16) u16 Vs[2][4096];
    __shared__ __align__(16) u16 Plds[4][1024];
    const int tid = threadIdx.x;
    const int lane = tid & 63;
    const int w = tid >> 6;
    const int lr = lane & 15, lg = lane >> 4;
    const int wg = (blockIdx.x & 7) * 128 + (blockIdx.x >> 3);
    const int qt = wg & 31;
    const int bh = wg >> 5;
    const int b = bh >> 4, h = bh & 15;
    const int qb = qt * 64 + w * 16;
    const float rate = decay_p[0];
    const float c1 = rate * 1.4426950408889634f;

    // q|k buffer: rows [4096], stride 2048 (q cols 0..1023, k cols 1024..2047)
    const u16* qmat = qkv + (size_t)b * 2048 * 2048 + h * 64;
    const u16* kmat = qmat + 1024;
    const u16* vtm = vt + (size_t)bh * 64 * 2048;
    const int* db = days + b * 2048;
    const float* ebase = edk + (b << 11);
    const float* tmx = tmaxc + b * 32;

    const int cp0 = (w * 2 + 0) * 64 + lane;
    const int cp1 = (w * 2 + 1) * 64 + lane;
    const int r0 = cp0 >> 3, c0 = cp0 & 7;
    const int r1 = cp1 >> 3, c1i = cp1 & 7;
    const u16* ksrc0 = kmat + (size_t)r0 * 2048 + ((c0 ^ (r0 & 7)) << 3);
    const u16* ksrc1 = kmat + (size_t)r1 * 2048 + ((c1i ^ (r1 & 7)) << 3);
    const u16* vsrc0 = vtm + (size_t)r0 * 2048 + ((c0 ^ (r0 & 7)) << 3);
    const u16* vsrc1 = vtm + (size_t)r1 * 2048 + ((c1i ^ (r1 & 7)) << 3);
    const int doff0 = (w * 2 + 0) * 512;
    const int doff1 = (w * 2 + 1) * 512;

#define STAGE(T, SLOT)                                                                 \
    do {                                                                               \
        __builtin_amdgcn_global_load_lds(                                              \
            (const __attribute__((address_space(1))) void*)(ksrc0 +                    \
                                                            (size_t)(T) * 64 * 2048), \
            (__attribute__((address_space(3))) void*)(&Ks[SLOT][doff0]), 16, 0, 0);    \
        __builtin_amdgcn_global_load_lds(                                              \
            (const __attribute__((address_space(1))) void*)(ksrc1 +                    \
                                                            (size_t)(T) * 64 * 2048), \
            (__attribute__((address_space(3))) void*)(&Ks[SLOT][doff1]), 16, 0, 0);    \
        __builtin_amdgcn_global_load_lds(                                              \
            (const __attribute__((address_space(1))) void*)(vsrc0 + (size_t)(T) * 64), \
            (__attribute__((address_space(3))) void*)(&Vs[SLOT][doff0]), 16, 0, 0);    \
        __builtin_amdgcn_global_load_lds(                                              \
            (const __attribute__((address_space(1))) void*)(vsrc1 + (size_t)(T) * 64), \
            (__attribute__((address_space(3))) void*)(&Vs[SLOT][doff1]), 16, 0, 0);    \
    } while (0)

    const float dq00_c = (float)db[qt * 64] * c1 + 3.0f;
    int t0;
    {
        const int l32 = lane & 31;
        float dm = tmx[l32];
        bool cnd = (lane < qt) && (dm < dq00_c - 20.0f);
        unsigned long long m = __ballot(cnd);
        t0 = (int)__builtin_ctzll(~m);
    }

    STAGE(t0, 0);

    bf16x8 bq0, bq1;
    {
        const u16* qp = qmat + (size_t)(qb + lr) * 2048 + lg * 8;
        bq0 = *(const bf16x8*)qp;
        bq1 = *(const bf16x8*)(qp + 32);
    }
    const float dq_c = (float)db[qb + lr] * c1 + 3.0f;

    const u16 pcu = f2bf(exp2f(-17.312340490667562f));
    const float pcr = bf2f(pcu);
    bf16x8 pconst;
#pragma unroll
    for (int i = 0; i < 8; ++i) pconst[i] = (short)pcu;

    float lp = (float)t0 * 16.0f * pcr;
    f32x4 acc[4];
#pragma unroll
    for (int c = 0; c < 4; ++c) {
        float vv = pcr * vps[((size_t)bh * 33 + t0) * 64 + c * 16 + lr];
        acc[c] = (f32x4){vv, vv, vv, vv};
    }

    for (int kt = t0; kt <= qt; ++kt) {
        const int cur = (kt - t0) & 1;
        if (kt < qt) {
            STAGE(kt + 1, cur ^ 1);
            asm volatile("s_waitcnt vmcnt(4)" ::: "memory");
        } else {
            asm volatile("s_waitcnt vmcnt(0)" ::: "memory");
        }
        __builtin_amdgcn_s_barrier();
        const float dkmax_c = tmx[kt];
        const float eqt = exp2f(dkmax_c - dq_c);
        attn_tile(Ks[cur], Vs[cur], Plds[w], ebase + kt * 64, eqt, dkmax_c, pconst,
                  pcr, bq0, bq1, dq_c, w * 16 + lr, kt == qt, lp, acc, lr, lg);
        __builtin_amdgcn_s_barrier();
    }
#undef STAGE

    float l_full = lp + __shfl_xor(lp, 16);
    l_full += __shfl_xor(l_full, 32);
    float inv_[4];
#pragma unroll
    for (int r = 0; r < 4; ++r) inv_[r] = 1.0f / __shfl(l_full, lg * 4 + r);
#pragma unroll
    for (int c = 0; c < 4; ++c)
#pragma unroll
        for (int r = 0; r < 4; ++r) {
            const int qg = qb + lg * 4 + r;
            attn_out[(size_t)(b * 2048 + qg) * 1024 + h * 64 + c * 16 + lr] =
                f2bf(acc[c][r] * inv_[r]);
        }
}

// ---------------- launch -----------------------------------------------------------
extern "C" void kernel_launch(void* const* d_in, const int* in_sizes, int n_in,
                              void* d_out, int out_size, void* d_ws, size_t ws_size,
                              hipStream_t stream) {
    const float* x = (const float*)d_in[0];
    const float* Wq = (const float*)d_in[1];
    const float* bq = (const float*)d_in[2];
    const float* Wk = (const float*)d_in[3];
    const float* bk = (const float*)d_in[4];
    const float* Wv = (const float*)d_in[5];
    const float* bv = (const float*)d_in[6];
    const float* Wo = (const float*)d_in[7];
    const float* bo = (const float*)d_in[8];
    const float* decay = (const float*)d_in[9];
    const int* days = (const int*)d_in[11];
    float* out = (float*)d_out;

    char* ws = (char*)d_ws;
    u16* xb = (u16*)(ws);                    //  8 MB: x bf16 [4096][1024]
    u16* wqkv = (u16*)(ws + 8388608);        //  6 MB: [Wq;Wk;Wv] bf16 [3072][1024]
    u16* wo = (u16*)(ws + 14680064);         //  2 MB: Wo bf16 [1024][1024]
    u16* qkb = (u16*)(ws + 16777216);        // 16 MB: q|k bf16 [4096][2048]
    u16* vtb = (u16*)(ws + 41943040);        //  8 MB: Vt bf16 [32][64][2048]
    u16* attb = (u16*)(ws + 50331648);       //  8 MB: attn out bf16 [4096][1024]
    float* vpsb = (float*)(ws + 58720256);   // 270 KB: V prefix sums [32][33][64]
    float* edkb = (float*)(ws + 58990592);   // 16 KB: edk [2][2048]
    float* tmaxb = (float*)(ws + 59006976);  // 256 B: tilemax*c1 [2][32]

    convert_all_k<<<8192, 256, 0, stream>>>(x, Wq, Wk, Wv, Wo, xb, wqkv, wo);
    edk_k<<<16, 256, 0, stream>>>(days, decay, edkb, tmaxb);

    gemm_qkv<<<768, 512, 0, stream>>>(xb, wqkv, bq, bk, bv, days, qkb, vtb, 4096,
                                      3072, 1024);
    vps_k<<<64, 256, 0, stream>>>(vtb, vpsb);
    attn_k<<<1024, 256, 0, stream>>>(qkb, vtb, days, decay, vpsb, edkb, tmaxb, attb);
    gemm_out<<<256, 512, 0, stream>>>(attb, wo, bo, out, 4096, 1024, 1024);
}